// Round 7
// baseline (187.291 us; speedup 1.0000x reference)
//
#include <hip/hip_runtime.h>

#define CIN 256
#define COUT 128
#define BSH2 9
#define BN2 512            // nodes per level-2 bucket
#define NBA 256            // allocated level-1 bins (nb1 <= 256)
#define TILE_E 8192        // edges per histogram/scatter tile

typedef __attribute__((ext_vector_type(8))) short short8;
typedef __attribute__((ext_vector_type(4))) float f32x4;

// bf16 helpers (manual, RNE)
__device__ __forceinline__ unsigned f2bf(float x) {
    unsigned u = __float_as_uint(x);
    unsigned r = ((u >> 16) & 1u) + 0x7fffu;
    return (u + r) >> 16;
}
__device__ __forceinline__ float bflo(unsigned u) { return __uint_as_float(u << 16); }
__device__ __forceinline__ float bfhi(unsigned u) { return __uint_as_float(u & 0xffff0000u); }

// ---------------- level-1: tile histograms over coarse buckets ----------------

__global__ __launch_bounds__(256) void k_hist1(const int* __restrict__ dst,
                                               int* __restrict__ histT, int e, int nt) {
    __shared__ int h[NBA];
    const int tid = threadIdx.x;
    const int t = blockIdx.x;
    h[tid] = 0;
    __syncthreads();
    const int lo = t * TILE_E;
    const int hi = min(lo + TILE_E, e);
    for (int i = lo + tid; i < hi; i += 256)
        atomicAdd(&h[dst[i] >> BSH2], 1);
    __syncthreads();
    histT[tid * nt + t] = h[tid];   // bucket-major for scan
}

// per-bucket parallel scan over tiles: baseT = local exclusive prefix, tot[b] = bucket total
__global__ __launch_bounds__(256) void k_scanA(const int* __restrict__ histT,
                                               int* __restrict__ baseT,
                                               int* __restrict__ tot, int nt) {
    __shared__ int v[256];
    const int b = blockIdx.x;
    const int tid = threadIdx.x;
    int carry = 0;
    for (int c0 = 0; c0 < nt; c0 += 256) {
        int t = c0 + tid;
        int x = (t < nt) ? histT[b * nt + t] : 0;
        v[tid] = x;
        __syncthreads();
        for (int off = 1; off < 256; off <<= 1) {
            int add = (tid >= off) ? v[tid - off] : 0;
            __syncthreads();
            v[tid] += add;
            __syncthreads();
        }
        if (t < nt) baseT[b * nt + t] = carry + v[tid] - x;   // exclusive prefix
        carry += v[255];
        __syncthreads();
    }
    if (tid == 0) tot[b] = carry;
}

// single small block: exclusive scan of 256 bucket totals -> bbase
__global__ __launch_bounds__(256) void k_scanB(const int* __restrict__ tot,
                                               int* __restrict__ bbase, int e) {
    __shared__ int v[256];
    const int tid = threadIdx.x;
    int x = tot[tid];
    v[tid] = x;
    __syncthreads();
    for (int off = 1; off < 256; off <<= 1) {
        int add = (tid >= off) ? v[tid - off] : 0;
        __syncthreads();
        v[tid] += add;
        __syncthreads();
    }
    bbase[tid] = v[tid] - x;
    if (tid == 0) bbase[NBA] = e;
}

// scatter edges into bucket regions as packed records: (dlow<<17)|src
__global__ __launch_bounds__(256) void k_scatter1(const int* __restrict__ src,
                                                  const int* __restrict__ dst,
                                                  const int* __restrict__ baseT,
                                                  const int* __restrict__ bbase,
                                                  int* __restrict__ etmp, int e, int nt) {
    __shared__ int cur[NBA];
    const int tid = threadIdx.x;
    const int t = blockIdx.x;
    cur[tid] = bbase[tid] + baseT[tid * nt + t];
    __syncthreads();
    const int lo = t * TILE_E;
    const int hi = min(lo + TILE_E, e);
    for (int i = lo + tid; i < hi; i += 256) {
        int d = dst[i];
        int p = atomicAdd(&cur[d >> BSH2], 1);
        etmp[p] = ((d & (BN2 - 1)) << 17) | src[i];
    }
}

// ---------------- level-2 phase A: per-bucket node histogram -> ecnt/dinv/offset ----------------

__global__ __launch_bounds__(256) void k_bbuild_a(const int* __restrict__ etmp,
                                                  const int* __restrict__ bbase,
                                                  int* __restrict__ ecnt,
                                                  float* __restrict__ dinv,
                                                  int* __restrict__ offset, int n) {
    __shared__ int h[BN2];
    __shared__ int val[256];
    __shared__ int sc[BN2];
    const int b = blockIdx.x;
    const int tid = threadIdx.x;
    const int base = bbase[b];
    const int cnt = bbase[b + 1] - base;

    h[tid] = 0; h[tid + 256] = 0;
    __syncthreads();
    for (int i = tid; i < cnt; i += 256)
        atomicAdd(&h[etmp[base + i] >> 17], 1);
    __syncthreads();
    val[tid] = h[2 * tid] + h[2 * tid + 1];
    __syncthreads();
    for (int off = 1; off < 256; off <<= 1) {
        int add = (tid >= off) ? val[tid - off] : 0;
        __syncthreads();
        val[tid] += add;
        __syncthreads();
    }
    int excl = (tid == 0) ? 0 : val[tid - 1];
    sc[2 * tid] = excl;
    sc[2 * tid + 1] = excl + h[2 * tid];
    __syncthreads();
#pragma unroll
    for (int q = 0; q < 2; q++) {
        int nd = 2 * tid + q;
        int v = (b << BSH2) + nd;
        if (v < n) {
            ecnt[v] = h[nd];
            dinv[v] = rsqrtf((float)(h[nd] + 1));
            offset[v] = base + sc[nd];
        }
    }
}

// ---------------- level-2 phase B: place src into final CSR ----------------

__global__ __launch_bounds__(256) void k_bbuild_b(const int* __restrict__ etmp,
                                                  const int* __restrict__ bbase,
                                                  const int* __restrict__ offset,
                                                  int* __restrict__ src_csr, int n) {
    __shared__ int sc[BN2];
    __shared__ int cur[BN2];
    const int b = blockIdx.x;
    const int tid = threadIdx.x;
    const int base = bbase[b];
    const int cnt = bbase[b + 1] - base;

#pragma unroll
    for (int q = 0; q < 2; q++) {
        int nd = 2 * tid + q;
        int v = (b << BSH2) + nd;
        sc[nd] = (v < n) ? (offset[v] - base) : 0;
        cur[nd] = 0;
    }
    __syncthreads();
    for (int i = tid; i < cnt; i += 256) {
        int pk = etmp[base + i];
        int dl = pk >> 17;
        int p = atomicAdd(&cur[dl], 1);
        src_csr[base + sc[dl] + p] = pk & 0x1FFFF;
    }
}

// ---------------- W pre-pack into MFMA B-fragment order ----------------

__global__ __launch_bounds__(256) void k_packW(const float* __restrict__ W,
                                               uint4* __restrict__ Wp) {
    int t = blockIdx.x * 256 + threadIdx.x;   // 0..4095: (kt,nt,lane)
    int lane = t & 63;
    int nt = (t >> 6) & 7;
    int kt = t >> 9;
    int kbase = kt * 32 + (lane >> 4) * 8;
    int col = nt * 16 + (lane & 15);
    unsigned o[4];
#pragma unroll
    for (int jj = 0; jj < 4; jj++) {
        float a = W[(size_t)(kbase + 2 * jj) * COUT + col];
        float b = W[(size_t)(kbase + 2 * jj + 1) * COUT + col];
        o[jj] = f2bf(a) | (f2bf(b) << 16);
    }
    Wp[t] = make_uint4(o[0], o[1], o[2], o[3]);
}

// ---------------- MFMA GEMM: XW = X @ W, bf16 output ----------------

__global__ __launch_bounds__(256) void k_gemm_mfma(const float* __restrict__ X,
                                                   const uint4* __restrict__ Wp,
                                                   unsigned short* __restrict__ XWb, int n) {
    const int wave = threadIdx.x >> 6;
    const int lane = threadIdx.x & 63;
    const int row0 = blockIdx.x * 64 + wave * 16;
    int arow = row0 + (lane & 15);
    if (arow >= n) arow = n - 1;            // clamp (stores are masked)
    const int kgrp = (lane >> 4) * 8;

    f32x4 acc[8];
#pragma unroll
    for (int i = 0; i < 8; i++) acc[i] = (f32x4)0.f;

    const float* xptr = X + (size_t)arow * CIN + kgrp;

    union U { unsigned u[4]; short8 s; };

#pragma unroll
    for (int kt = 0; kt < 8; kt++) {
        float4 a0 = *(const float4*)(xptr + kt * 32);
        float4 a1 = *(const float4*)(xptr + kt * 32 + 4);
        U au;
        au.u[0] = f2bf(a0.x) | (f2bf(a0.y) << 16);
        au.u[1] = f2bf(a0.z) | (f2bf(a0.w) << 16);
        au.u[2] = f2bf(a1.x) | (f2bf(a1.y) << 16);
        au.u[3] = f2bf(a1.z) | (f2bf(a1.w) << 16);
        short8 afrag = au.s;
#pragma unroll
        for (int nt = 0; nt < 8; nt++) {
            uint4 b = Wp[(kt * 8 + nt) * 64 + lane];
            U bu;
            bu.u[0] = b.x; bu.u[1] = b.y; bu.u[2] = b.z; bu.u[3] = b.w;
            acc[nt] = __builtin_amdgcn_mfma_f32_16x16x32_bf16(afrag, bu.s, acc[nt], 0, 0, 0);
        }
    }

    // C/D: col = lane&15, row = (lane>>4)*4 + reg
    const int r0 = (lane >> 4) * 4;
    const int c = lane & 15;
#pragma unroll
    for (int nt = 0; nt < 8; nt++) {
#pragma unroll
        for (int r = 0; r < 4; r++) {
            int row = row0 + r0 + r;
            if (row < n)
                XWb[(size_t)row * COUT + nt * 16 + c] = (unsigned short)f2bf(acc[nt][r]);
        }
    }
}

// ---------------- aggregation: one wave per node, unroll x8, dinv broadcast ----------------

__global__ __launch_bounds__(256) void k_agg(const unsigned* __restrict__ XWb,
                                             const float* __restrict__ dinv,
                                             const int* __restrict__ ecnt,
                                             const int* __restrict__ offset,
                                             const int* __restrict__ src_csr,
                                             const float* __restrict__ bias,
                                             const float* __restrict__ alpha,
                                             float* __restrict__ out, int n) {
    const int wave = threadIdx.x >> 6;
    const int lane = threadIdx.x & 63;
    const int v = blockIdx.x * 4 + wave;
    if (v >= n) return;

    const float dv = dinv[v];
    float ax, ay;
    {
        float nrm = dv * dv;
        unsigned u = XWb[(size_t)v * 64 + lane];
        ax = nrm * bflo(u);
        ay = nrm * bfhi(u);
    }
    const int beg = offset[v];
    const int cnt = ecnt[v];
    int e = 0;
    for (; e + 8 <= cnt; e += 8) {
        int s[8];
#pragma unroll
        for (int q = 0; q < 8; q++) s[q] = src_csr[beg + e + q];
        float nr[8];
#pragma unroll
        for (int q = 0; q < 8; q++) nr[q] = dinv[s[q]];
        unsigned u[8];
#pragma unroll
        for (int q = 0; q < 8; q++) u[q] = XWb[(size_t)s[q] * 64 + lane];
#pragma unroll
        for (int q = 0; q < 8; q++) {
            float nn = nr[q] * dv;
            ax += nn * bflo(u[q]);
            ay += nn * bfhi(u[q]);
        }
    }
    for (; e < cnt; e++) {
        int s = src_csr[beg + e];
        float nn = dinv[s] * dv;
        unsigned u = XWb[(size_t)s * 64 + lane];
        ax += nn * bflo(u);
        ay += nn * bfhi(u);
    }
    float2 bb = *(const float2*)&bias[lane * 2];
    float2 aa = *(const float2*)&alpha[lane * 2];
    float o0 = ax + bb.x;
    float o1 = ay + bb.y;
    o0 = o0 > 0.f ? o0 : aa.x * o0;
    o1 = o1 > 0.f ? o1 : aa.y * o1;
    *(float2*)&out[(size_t)v * COUT + lane * 2] = make_float2(o0, o1);
}

// ---------------- launch ----------------

extern "C" void kernel_launch(void* const* d_in, const int* in_sizes, int n_in,
                              void* d_out, int out_size, void* d_ws, size_t ws_size,
                              hipStream_t stream) {
    const float* x     = (const float*)d_in[0];
    const int*   edge  = (const int*)d_in[1];
    const float* W     = (const float*)d_in[2];
    const float* bias  = (const float*)d_in[3];
    const float* alpha = (const float*)d_in[4];
    float* out = (float*)d_out;

    const int n = in_sizes[0] / CIN;       // 100000
    const int e = in_sizes[1] / 2;         // 1600000
    const int* src = edge;
    const int* dst = edge + e;
    const int nt  = (e + TILE_E - 1) / TILE_E;   // tiles
    const int nb1 = (n + BN2 - 1) >> BSH2;       // level-2 buckets (<= 256)

    // workspace layout (bytes); all chunk sizes multiples of 16
    char* ws = (char*)d_ws;
    unsigned* xwb   = (unsigned*)ws;                                   // n*64 u32 = 25.6 MB
    char* p = ws + (size_t)n * (COUT / 2) * 4;
    float* dinv     = (float*)p;            p += (size_t)n * 4;
    int*   ecnt     = (int*)p;              p += (size_t)n * 4;
    int*   offset   = (int*)p;              p += (size_t)n * 4;
    int*   src_csr  = (int*)p;              p += (size_t)e * 4;        // 6.4 MB final CSR
    int*   etmp     = (int*)p;              p += (size_t)e * 4;        // 6.4 MB staging
    uint4* wpack    = (uint4*)p;            p += 4096 * 16;            // 64 KB
    int*   histT    = (int*)p;              p += (size_t)NBA * nt * 4;
    int*   baseT    = (int*)p;              p += (size_t)NBA * nt * 4;
    int*   bbase    = (int*)p;              p += (size_t)(NBA + 1) * 4;
    int*   tot      = (int*)p;              p += (size_t)NBA * 4;

    const int TB = 256;
    k_hist1<<<nt, TB, 0, stream>>>(dst, histT, e, nt);
    k_scanA<<<NBA, TB, 0, stream>>>(histT, baseT, tot, nt);
    k_scanB<<<1, TB, 0, stream>>>(tot, bbase, e);
    k_scatter1<<<nt, TB, 0, stream>>>(src, dst, baseT, bbase, etmp, e, nt);
    k_bbuild_a<<<nb1, TB, 0, stream>>>(etmp, bbase, ecnt, dinv, offset, n);
    k_bbuild_b<<<nb1, TB, 0, stream>>>(etmp, bbase, offset, src_csr, n);
    k_packW<<<16, TB, 0, stream>>>(W, wpack);
    k_gemm_mfma<<<(n + 63) / 64, TB, 0, stream>>>(x, wpack, (unsigned short*)xwb, n);
    k_agg<<<(n + 3) / 4, TB, 0, stream>>>(xwb, dinv, ecnt, offset, src_csr, bias, alpha, out, n);
}

// Round 8
// 173.865 us; speedup vs baseline: 1.0772x; 1.0772x over previous
//
#include <hip/hip_runtime.h>

#define CIN 256
#define COUT 128
#define BSH2 9
#define BN2 512            // nodes per level-2 bucket
#define NBA 256            // allocated level-1 bins (nb1 <= 256)
#define TILE_E 8192        // edges per histogram/scatter tile

typedef __attribute__((ext_vector_type(8))) short short8;
typedef __attribute__((ext_vector_type(4))) float f32x4;

// bf16 helpers (manual, RNE)
__device__ __forceinline__ unsigned f2bf(float x) {
    unsigned u = __float_as_uint(x);
    unsigned r = ((u >> 16) & 1u) + 0x7fffu;
    return (u + r) >> 16;
}
__device__ __forceinline__ float bflo(unsigned u) { return __uint_as_float(u << 16); }
__device__ __forceinline__ float bfhi(unsigned u) { return __uint_as_float(u & 0xffff0000u); }

// ---------------- level-1: tile histograms over coarse buckets ----------------

__global__ __launch_bounds__(256) void k_hist1(const int* __restrict__ dst,
                                               int* __restrict__ histT, int e, int nt) {
    __shared__ int h[NBA];
    const int tid = threadIdx.x;
    const int t = blockIdx.x;
    h[tid] = 0;
    __syncthreads();
    const int lo = t * TILE_E;
    const int hi = min(lo + TILE_E, e);
    for (int i = lo + tid; i < hi; i += 256)
        atomicAdd(&h[dst[i] >> BSH2], 1);
    __syncthreads();
    histT[tid * nt + t] = h[tid];   // bucket-major for scan
}

// per-bucket parallel scan over tiles: baseT = local exclusive prefix, tot[b] = bucket total
__global__ __launch_bounds__(256) void k_scanA(const int* __restrict__ histT,
                                               int* __restrict__ baseT,
                                               int* __restrict__ tot, int nt) {
    __shared__ int v[256];
    const int b = blockIdx.x;
    const int tid = threadIdx.x;
    int carry = 0;
    for (int c0 = 0; c0 < nt; c0 += 256) {
        int t = c0 + tid;
        int x = (t < nt) ? histT[b * nt + t] : 0;
        v[tid] = x;
        __syncthreads();
        for (int off = 1; off < 256; off <<= 1) {
            int add = (tid >= off) ? v[tid - off] : 0;
            __syncthreads();
            v[tid] += add;
            __syncthreads();
        }
        if (t < nt) baseT[b * nt + t] = carry + v[tid] - x;   // exclusive prefix
        carry += v[255];
        __syncthreads();
    }
    if (tid == 0) tot[b] = carry;
}

// single small block: exclusive scan of 256 bucket totals -> bbase
__global__ __launch_bounds__(256) void k_scanB(const int* __restrict__ tot,
                                               int* __restrict__ bbase, int e) {
    __shared__ int v[256];
    const int tid = threadIdx.x;
    int x = tot[tid];
    v[tid] = x;
    __syncthreads();
    for (int off = 1; off < 256; off <<= 1) {
        int add = (tid >= off) ? v[tid - off] : 0;
        __syncthreads();
        v[tid] += add;
        __syncthreads();
    }
    bbase[tid] = v[tid] - x;
    if (tid == 0) bbase[NBA] = e;
}

// scatter edges into bucket regions as packed records: (dlow<<17)|src
__global__ __launch_bounds__(256) void k_scatter1(const int* __restrict__ src,
                                                  const int* __restrict__ dst,
                                                  const int* __restrict__ baseT,
                                                  const int* __restrict__ bbase,
                                                  int* __restrict__ etmp, int e, int nt) {
    __shared__ int cur[NBA];
    const int tid = threadIdx.x;
    const int t = blockIdx.x;
    cur[tid] = bbase[tid] + baseT[tid * nt + t];
    __syncthreads();
    const int lo = t * TILE_E;
    const int hi = min(lo + TILE_E, e);
    for (int i = lo + tid; i < hi; i += 256) {
        int d = dst[i];
        int p = atomicAdd(&cur[d >> BSH2], 1);
        etmp[p] = ((d & (BN2 - 1)) << 17) | src[i];
    }
}

// ---------------- level-2 phase A: per-bucket node histogram -> ecnt/dinv/offset ----------------

__global__ __launch_bounds__(256) void k_bbuild_a(const int* __restrict__ etmp,
                                                  const int* __restrict__ bbase,
                                                  int* __restrict__ ecnt,
                                                  float* __restrict__ dinv,
                                                  int* __restrict__ offset, int n) {
    __shared__ int h[BN2];
    __shared__ int val[256];
    __shared__ int sc[BN2];
    const int b = blockIdx.x;
    const int tid = threadIdx.x;
    const int base = bbase[b];
    const int cnt = bbase[b + 1] - base;

    h[tid] = 0; h[tid + 256] = 0;
    __syncthreads();
    for (int i = tid; i < cnt; i += 256)
        atomicAdd(&h[etmp[base + i] >> 17], 1);
    __syncthreads();
    val[tid] = h[2 * tid] + h[2 * tid + 1];
    __syncthreads();
    for (int off = 1; off < 256; off <<= 1) {
        int add = (tid >= off) ? val[tid - off] : 0;
        __syncthreads();
        val[tid] += add;
        __syncthreads();
    }
    int excl = (tid == 0) ? 0 : val[tid - 1];
    sc[2 * tid] = excl;
    sc[2 * tid + 1] = excl + h[2 * tid];
    __syncthreads();
#pragma unroll
    for (int q = 0; q < 2; q++) {
        int nd = 2 * tid + q;
        int v = (b << BSH2) + nd;
        if (v < n) {
            ecnt[v] = h[nd];
            dinv[v] = rsqrtf((float)(h[nd] + 1));
            offset[v] = base + sc[nd];
        }
    }
}

// ---------------- level-2 phase B: place (src, fused norm) into final CSR ----------------

__global__ __launch_bounds__(256) void k_bbuild_b(const int* __restrict__ etmp,
                                                  const int* __restrict__ bbase,
                                                  const int* __restrict__ offset,
                                                  const float* __restrict__ dinv,
                                                  int2* __restrict__ edges, int n) {
    __shared__ int sc[BN2];
    __shared__ int cur[BN2];
    __shared__ float ldinv[BN2];
    const int b = blockIdx.x;
    const int tid = threadIdx.x;
    const int base = bbase[b];
    const int cnt = bbase[b + 1] - base;

#pragma unroll
    for (int q = 0; q < 2; q++) {
        int nd = 2 * tid + q;
        int v = (b << BSH2) + nd;
        sc[nd] = (v < n) ? (offset[v] - base) : 0;
        ldinv[nd] = (v < n) ? dinv[v] : 0.f;
        cur[nd] = 0;
    }
    __syncthreads();
    for (int i = tid; i < cnt; i += 256) {
        int pk = etmp[base + i];
        int dl = pk >> 17;
        int s = pk & 0x1FFFF;
        int p = atomicAdd(&cur[dl], 1);
        float nrm = dinv[s] * ldinv[dl];
        edges[base + sc[dl] + p] = make_int2(s, __float_as_int(nrm));
    }
}

// ---------------- W pre-pack into MFMA B-fragment order ----------------

__global__ __launch_bounds__(256) void k_packW(const float* __restrict__ W,
                                               uint4* __restrict__ Wp) {
    int t = blockIdx.x * 256 + threadIdx.x;   // 0..4095: (kt,nt,lane)
    int lane = t & 63;
    int nt = (t >> 6) & 7;
    int kt = t >> 9;
    int kbase = kt * 32 + (lane >> 4) * 8;
    int col = nt * 16 + (lane & 15);
    unsigned o[4];
#pragma unroll
    for (int jj = 0; jj < 4; jj++) {
        float a = W[(size_t)(kbase + 2 * jj) * COUT + col];
        float b = W[(size_t)(kbase + 2 * jj + 1) * COUT + col];
        o[jj] = f2bf(a) | (f2bf(b) << 16);
    }
    Wp[t] = make_uint4(o[0], o[1], o[2], o[3]);
}

// ---------------- MFMA GEMM: XW = X @ W, bf16 output ----------------

__global__ __launch_bounds__(256) void k_gemm_mfma(const float* __restrict__ X,
                                                   const uint4* __restrict__ Wp,
                                                   unsigned short* __restrict__ XWb, int n) {
    const int wave = threadIdx.x >> 6;
    const int lane = threadIdx.x & 63;
    const int row0 = blockIdx.x * 64 + wave * 16;
    int arow = row0 + (lane & 15);
    if (arow >= n) arow = n - 1;            // clamp (stores are masked)
    const int kgrp = (lane >> 4) * 8;

    f32x4 acc[8];
#pragma unroll
    for (int i = 0; i < 8; i++) acc[i] = (f32x4)0.f;

    const float* xptr = X + (size_t)arow * CIN + kgrp;

    union U { unsigned u[4]; short8 s; };

#pragma unroll
    for (int kt = 0; kt < 8; kt++) {
        float4 a0 = *(const float4*)(xptr + kt * 32);
        float4 a1 = *(const float4*)(xptr + kt * 32 + 4);
        U au;
        au.u[0] = f2bf(a0.x) | (f2bf(a0.y) << 16);
        au.u[1] = f2bf(a0.z) | (f2bf(a0.w) << 16);
        au.u[2] = f2bf(a1.x) | (f2bf(a1.y) << 16);
        au.u[3] = f2bf(a1.z) | (f2bf(a1.w) << 16);
        short8 afrag = au.s;
#pragma unroll
        for (int nt = 0; nt < 8; nt++) {
            uint4 b = Wp[(kt * 8 + nt) * 64 + lane];
            U bu;
            bu.u[0] = b.x; bu.u[1] = b.y; bu.u[2] = b.z; bu.u[3] = b.w;
            acc[nt] = __builtin_amdgcn_mfma_f32_16x16x32_bf16(afrag, bu.s, acc[nt], 0, 0, 0);
        }
    }

    // C/D: col = lane&15, row = (lane>>4)*4 + reg
    const int r0 = (lane >> 4) * 4;
    const int c = lane & 15;
#pragma unroll
    for (int nt = 0; nt < 8; nt++) {
#pragma unroll
        for (int r = 0; r < 4; r++) {
            int row = row0 + r0 + r;
            if (row < n)
                XWb[(size_t)row * COUT + nt * 16 + c] = (unsigned short)f2bf(acc[nt][r]);
        }
    }
}

// ---------------- aggregation: one wave per node, fused-norm records, unroll x8 ----------------

__global__ __launch_bounds__(256) void k_agg(const unsigned* __restrict__ XWb,
                                             const float* __restrict__ dinv,
                                             const int* __restrict__ ecnt,
                                             const int* __restrict__ offset,
                                             const int2* __restrict__ edges,
                                             const float* __restrict__ bias,
                                             const float* __restrict__ alpha,
                                             float* __restrict__ out, int n) {
    const int wave = threadIdx.x >> 6;
    const int lane = threadIdx.x & 63;
    const int v = blockIdx.x * 4 + wave;
    if (v >= n) return;

    const float dv = dinv[v];
    float ax, ay;
    {
        float nrm = dv * dv;
        unsigned u = XWb[(size_t)v * 64 + lane];
        ax = nrm * bflo(u);
        ay = nrm * bfhi(u);
    }
    const int beg = offset[v];
    const int cnt = ecnt[v];
    int e = 0;
    for (; e + 8 <= cnt; e += 8) {
        int2 r[8];
#pragma unroll
        for (int q = 0; q < 8; q++) r[q] = edges[beg + e + q];
        unsigned u[8];
#pragma unroll
        for (int q = 0; q < 8; q++) u[q] = XWb[(size_t)r[q].x * 64 + lane];
#pragma unroll
        for (int q = 0; q < 8; q++) {
            float nn = __int_as_float(r[q].y);
            ax += nn * bflo(u[q]);
            ay += nn * bfhi(u[q]);
        }
    }
    for (; e + 4 <= cnt; e += 4) {
        int2 r[4];
#pragma unroll
        for (int q = 0; q < 4; q++) r[q] = edges[beg + e + q];
        unsigned u[4];
#pragma unroll
        for (int q = 0; q < 4; q++) u[q] = XWb[(size_t)r[q].x * 64 + lane];
#pragma unroll
        for (int q = 0; q < 4; q++) {
            float nn = __int_as_float(r[q].y);
            ax += nn * bflo(u[q]);
            ay += nn * bfhi(u[q]);
        }
    }
    for (; e < cnt; e++) {
        int2 ee = edges[beg + e];
        unsigned u = XWb[(size_t)ee.x * 64 + lane];
        float nn = __int_as_float(ee.y);
        ax += nn * bflo(u);
        ay += nn * bfhi(u);
    }
    float2 bb = *(const float2*)&bias[lane * 2];
    float2 aa = *(const float2*)&alpha[lane * 2];
    float o0 = ax + bb.x;
    float o1 = ay + bb.y;
    o0 = o0 > 0.f ? o0 : aa.x * o0;
    o1 = o1 > 0.f ? o1 : aa.y * o1;
    *(float2*)&out[(size_t)v * COUT + lane * 2] = make_float2(o0, o1);
}

// ---------------- launch ----------------

extern "C" void kernel_launch(void* const* d_in, const int* in_sizes, int n_in,
                              void* d_out, int out_size, void* d_ws, size_t ws_size,
                              hipStream_t stream) {
    const float* x     = (const float*)d_in[0];
    const int*   edge  = (const int*)d_in[1];
    const float* W     = (const float*)d_in[2];
    const float* bias  = (const float*)d_in[3];
    const float* alpha = (const float*)d_in[4];
    float* out = (float*)d_out;

    const int n = in_sizes[0] / CIN;       // 100000
    const int e = in_sizes[1] / 2;         // 1600000
    const int* src = edge;
    const int* dst = edge + e;
    const int nt  = (e + TILE_E - 1) / TILE_E;   // tiles
    const int nb1 = (n + BN2 - 1) >> BSH2;       // level-2 buckets (<= 256)

    // workspace layout (bytes); all chunk sizes multiples of 16
    char* ws = (char*)d_ws;
    unsigned* xwb   = (unsigned*)ws;                                   // n*64 u32 = 25.6 MB
    char* p = ws + (size_t)n * (COUT / 2) * 4;
    float* dinv     = (float*)p;            p += (size_t)n * 4;
    int*   ecnt     = (int*)p;              p += (size_t)n * 4;
    int*   offset   = (int*)p;              p += (size_t)n * 4;
    int2*  edges    = (int2*)p;             p += (size_t)e * 8;        // 12.8 MB final CSR
    int*   etmp     = (int*)p;              p += (size_t)e * 4;        // 6.4 MB staging
    uint4* wpack    = (uint4*)p;            p += 4096 * 16;            // 64 KB
    int*   histT    = (int*)p;              p += (size_t)NBA * nt * 4;
    int*   baseT    = (int*)p;              p += (size_t)NBA * nt * 4;
    int*   bbase    = (int*)p;              p += (size_t)(NBA + 1) * 4;
    int*   tot      = (int*)p;              p += (size_t)NBA * 4;

    const int TB = 256;
    k_hist1<<<nt, TB, 0, stream>>>(dst, histT, e, nt);
    k_scanA<<<NBA, TB, 0, stream>>>(histT, baseT, tot, nt);
    k_scanB<<<1, TB, 0, stream>>>(tot, bbase, e);
    k_scatter1<<<nt, TB, 0, stream>>>(src, dst, baseT, bbase, etmp, e, nt);
    k_bbuild_a<<<nb1, TB, 0, stream>>>(etmp, bbase, ecnt, dinv, offset, n);
    k_bbuild_b<<<nb1, TB, 0, stream>>>(etmp, bbase, offset, dinv, edges, n);
    k_packW<<<16, TB, 0, stream>>>(W, wpack);
    k_gemm_mfma<<<(n + 63) / 64, TB, 0, stream>>>(x, wpack, (unsigned short*)xwb, n);
    k_agg<<<(n + 3) / 4, TB, 0, stream>>>(xwb, dinv, ecnt, offset, edges, bias, alpha, out, n);
}